// Round 1
// baseline (193.564 us; speedup 1.0000x reference)
//
#include <hip/hip_runtime.h>
#include <hip/hip_bf16.h>

// ============================================================================
// fused stride-2 "transposed conv" + bias + channel-softmax + sigmoid
//
// Key insight: PAD==OUT_PAD==1 => t_h = h, divisibility mask kills every odd
// h or odd w output => those are a CONSTANT vector sigmoid(2*softmax(bias)).
// Even-even outputs (p,q)=(h/2,w/2) in [0,65)^2 are a dense 4x4 conv:
//   O[n,c,p,q] = sum_{ic,kh,kw, 0<=p-kh<64, 0<=q-kw<64} x[n,ic,p-kh,q-kw]*W[c,ic,kh,kw]
//
// Numerics: bf16 hi/lo split (3 MFMAs: Ahi*Bhi + Ahi*Blo + Alo*Bhi), fp32 acc.
// Logit error ~2e-4 << 1.76e-2 threshold.
// ============================================================================

typedef __bf16 bf16x8 __attribute__((ext_vector_type(8)));
typedef float  f32x4  __attribute__((ext_vector_type(4)));
typedef unsigned short ushort_t;

#define TILE_P 8
#define TILE_Q 16
#define PATCH_R 11                 // TILE_P + 3
#define PATCH_C 19                 // TILE_Q + 3
#define XELEMS (PATCH_R*PATCH_C*64)   // 13376 bf16 per hi/lo plane
#define X_LO_OFF (XELEMS*2)           // 26752 bytes
#define LOGIT_LD 132                  // fp32 pad: 16B-aligned rows, 2-way-max banks
#define LOGIT_BYTES (128*LOGIT_LD*4)  // 67584
#define CONST_OFF LOGIT_BYTES         // 67584
#define INV_OFF   (CONST_OFF+512)     // 68096
#define SMEM_BYTES (INV_OFF+512)      // 68608  (2 blocks/CU: 137 KB <= 160 KB)
#define WSW_BYTES (16*8*2*2*64*16)    // 524288: [tap][ct8][ch2][hi/lo][lane64][16B]

// ---- prep: weight -> MFMA-fragment-ordered bf16 hi/lo in workspace ----------
// A-frag (16x16x32, M=cout,K=ic): lane l holds A[row=l&15][k=(l>>4)*8+i], i<8.
__global__ void prep_w_kernel(const float* __restrict__ w, ushort_t* __restrict__ wsW) {
    int slot = blockIdx.x * 256 + threadIdx.x;      // 16384 slots
    int lane = slot & 63;
    int ch   = (slot >> 6) & 1;
    int ct   = (slot >> 7) & 7;
    int tap  = slot >> 10;
    int kh = tap >> 2, kw = tap & 3;
    int cout = ct * 16 + (lane & 15);
    bf16x8 hi, lo;
#pragma unroll
    for (int i = 0; i < 8; ++i) {
        int ic = ch * 32 + (lane >> 4) * 8 + i;
        float v = w[((cout * 64 + ic) * 4 + kh) * 4 + kw];
        __bf16 h = (__bf16)v;
        hi[i] = h;
        lo[i] = (__bf16)(v - (float)h);
    }
    bf16x8* wf = (bf16x8*)wsW;
    int off = (((tap * 8 + ct) * 2 + ch) * 2) * 64 + lane;  // hi block
    wf[off]      = hi;
    wf[off + 64] = lo;
}

// ---- prep: const vector sigmoid(2*softmax(bias)) ---------------------------
__global__ void prep_const_kernel(const float* __restrict__ bias, float* __restrict__ wsc) {
    __shared__ float red[128];
    int t = threadIdx.x;
    red[t] = bias[t];
    __syncthreads();
    float m = -3.4e38f;
    for (int i = 0; i < 128; ++i) m = fmaxf(m, red[i]);
    float e = __expf(red[t] - m);
    __syncthreads();
    red[t] = e;
    __syncthreads();
    float s = 0.f;
    for (int i = 0; i < 128; ++i) s += red[i];
    float v = e / s;
    wsc[t] = 1.0f / (1.0f + __expf(-2.0f * v));
}

// ---- main: conv(MFMA) + softmax + sigmoid for even-h rows ------------------
__launch_bounds__(256, 2)
__global__ void conv_main_kernel(const float* __restrict__ x,
                                 const float* __restrict__ bias,
                                 const ushort_t* __restrict__ wsW,
                                 const float* __restrict__ wsc,
                                 float* __restrict__ out) {
    extern __shared__ char smem[];
    ushort_t* xhi   = (ushort_t*)smem;
    ushort_t* xlo   = (ushort_t*)(smem + X_LO_OFF);
    float*    logit = (float*)smem;                 // reuses X region after K-loop
    float*    cconst= (float*)(smem + CONST_OFF);
    float*    inv   = (float*)(smem + INV_OFF);

    const int tid = threadIdx.x;
    const int n   = blockIdx.z;
    const int p0  = blockIdx.y * TILE_P;
    const int q0  = blockIdx.x * TILE_Q;

    // ---- stage X patch: hi/lo bf16, ic-group XOR swizzle (b128-floor reads) ----
    const float* xg = x + (size_t)n * 64 * 64 * 64;
    for (int grp = tid; grp < PATCH_R * PATCH_C * 8; grp += 256) {
        int r   = grp / (PATCH_C * 8);
        int rem = grp - r * (PATCH_C * 8);
        int c   = rem >> 3;
        int g   = rem & 7;
        int row = p0 + r - 3;
        int col = q0 + c - 3;
        bool ok = (row >= 0) & (row < 64) & (col >= 0) & (col < 64);
        const float* src = xg + ((g * 8) << 12) + (row << 6) + col;  // ic stride 4096
        bf16x8 hi, lo;
#pragma unroll
        for (int i = 0; i < 8; ++i) {
            float v = ok ? src[i << 12] : 0.0f;
            __bf16 h = (__bf16)v;
            hi[i] = h;
            lo[i] = (__bf16)(v - (float)h);
        }
        int slot = ((r * PATCH_C + c) * 8 + (g ^ (c & 7))) * 8;     // elem index
        *(bf16x8*)(xhi + slot) = hi;
        *(bf16x8*)(xlo + slot) = lo;
    }
    if (tid < 128) cconst[tid] = wsc[tid];
    __syncthreads();

    // ---- K loop: 16 taps x 2 ic-chunks, no barriers (X is read-only) ----
    const int lane = tid & 63;
    const int wv   = tid >> 6;       // wave id: cout tiles 2*wv, 2*wv+1
    const int ltc  = lane & 15;      // B/D col (position)
    const int lg   = lane >> 4;      // k-group / D row-group

    f32x4 acc[2][8];
#pragma unroll
    for (int ct = 0; ct < 2; ++ct)
#pragma unroll
        for (int pt = 0; pt < 8; ++pt)
            acc[ct][pt] = (f32x4){0.f, 0.f, 0.f, 0.f};

    const bf16x8* wf = (const bf16x8*)wsW;

    for (int tap = 0; tap < 16; ++tap) {
        int kh = tap >> 2, kw = tap & 3;
        int cc = ltc + 3 - kw;       // patch col for this lane
        int c7 = cc & 7;
        int rb = 3 - kh;             // patch row base (pt adds 1 per row)
#pragma unroll
        for (int ch = 0; ch < 2; ++ch) {
            int a0 = (((tap * 8 + wv * 2 + 0) * 2 + ch) * 2) * 64 + lane;
            int a1 = (((tap * 8 + wv * 2 + 1) * 2 + ch) * 2) * 64 + lane;
            bf16x8 ahi0 = wf[a0], alo0 = wf[a0 + 64];
            bf16x8 ahi1 = wf[a1], alo1 = wf[a1 + 64];
            int g4 = ((ch << 2) | lg) ^ c7;
            int base = ((rb * PATCH_C + cc) * 8 + g4) * 8;  // elems; +1216/row
            const ushort_t* hp = xhi + base;
            const ushort_t* lp = xlo + base;
#pragma unroll
            for (int pt = 0; pt < 8; ++pt) {
                bf16x8 bhi = *(const bf16x8*)(hp + pt * (PATCH_C * 64));
                bf16x8 blo = *(const bf16x8*)(lp + pt * (PATCH_C * 64));
                acc[0][pt] = __builtin_amdgcn_mfma_f32_16x16x32_bf16(ahi0, bhi, acc[0][pt], 0, 0, 0);
                acc[0][pt] = __builtin_amdgcn_mfma_f32_16x16x32_bf16(ahi0, blo, acc[0][pt], 0, 0, 0);
                acc[0][pt] = __builtin_amdgcn_mfma_f32_16x16x32_bf16(alo0, bhi, acc[0][pt], 0, 0, 0);
                acc[1][pt] = __builtin_amdgcn_mfma_f32_16x16x32_bf16(ahi1, bhi, acc[1][pt], 0, 0, 0);
                acc[1][pt] = __builtin_amdgcn_mfma_f32_16x16x32_bf16(ahi1, blo, acc[1][pt], 0, 0, 0);
                acc[1][pt] = __builtin_amdgcn_mfma_f32_16x16x32_bf16(alo1, bhi, acc[1][pt], 0, 0, 0);
            }
        }
    }
    __syncthreads();   // all X reads done; safe to overwrite with logits

    // ---- acc(+bias) -> logit LDS. D layout: col=lane&15, row=(lane>>4)*4+reg ----
    {
        int colbase = wv * 32;
#pragma unroll
        for (int ct = 0; ct < 2; ++ct) {
            int col = colbase + ct * 16 + lg * 4;
            f32x4 bv;
#pragma unroll
            for (int rI = 0; rI < 4; ++rI) bv[rI] = bias[col + rI];
#pragma unroll
            for (int pt = 0; pt < 8; ++pt) {
                f32x4 v = acc[ct][pt] + bv;
                *(f32x4*)(logit + (pt * 16 + ltc) * LOGIT_LD + col) = v;
            }
        }
    }
    __syncthreads();

    // ---- softmax: 2 threads per position row of 128 channels ----
    {
        int pos  = tid >> 1;
        int half = tid & 1;
        float* rowp = logit + pos * LOGIT_LD + half * 64;
        float m = -3.4e38f;
#pragma unroll
        for (int i = 0; i < 16; ++i) {
            f32x4 v = *(f32x4*)(rowp + i * 4);
            m = fmaxf(m, fmaxf(fmaxf(v[0], v[1]), fmaxf(v[2], v[3])));
        }
        m = fmaxf(m, __shfl_xor(m, 1));
        float s = 0.f;
#pragma unroll
        for (int i = 0; i < 16; ++i) {
            f32x4 v = *(f32x4*)(rowp + i * 4);
            f32x4 e;
            e[0] = __expf(v[0] - m); e[1] = __expf(v[1] - m);
            e[2] = __expf(v[2] - m); e[3] = __expf(v[3] - m);
            s += e[0] + e[1] + e[2] + e[3];
            *(f32x4*)(rowp + i * 4) = e;
        }
        s += __shfl_xor(s, 1);
        if (half == 0) inv[pos] = 1.0f / s;
    }
    __syncthreads();

    // ---- write: even-h rows; (computed even-w, const odd-w) pairs ----
    for (int j = 0; j < 64; ++j) {
        int flat = j * 256 + tid;
        int c  = flat >> 7;
        int tr = (flat >> 4) & 7;
        int tc = flat & 15;
        int p = p0 + tr, q = q0 + tc;
        if (p < 65 && q < 65) {
            int pos = tr * 16 + tc;
            float v  = logit[pos * LOGIT_LD + c] * inv[pos];
            float sg = 1.0f / (1.0f + __expf(-2.0f * v));
            size_t o = (((size_t)(n * 128 + c) * 129) + 2 * p) * 129 + 2 * q;
            out[o] = sg;
            if (q < 64) out[o + 1] = cconst[c];
        }
    }
}

// ---- fill: odd-h rows are the constant vector ------------------------------
__global__ void fill_kernel(const float* __restrict__ wsc, float* __restrict__ out) {
    int rid  = blockIdx.x * 4 + (threadIdx.x >> 6);   // row id: [n][c][oh]
    int lane = threadIdx.x & 63;
    int n   = rid >> 13;            // /8192
    int rem = rid & 8191;
    int c   = rem >> 6;
    int oh  = ((rem & 63) << 1) + 1;
    float v = wsc[c];
    size_t base = ((size_t)(n * 128 + c) * 129 + oh) * 129;
    out[base + lane]      = v;
    out[base + 64 + lane] = v;
    if (lane == 0) out[base + 128] = v;
}

extern "C" void kernel_launch(void* const* d_in, const int* in_sizes, int n_in,
                              void* d_out, int out_size, void* d_ws, size_t ws_size,
                              hipStream_t stream) {
    const float* x    = (const float*)d_in[0];
    const float* w    = (const float*)d_in[1];
    const float* bias = (const float*)d_in[2];
    float* out = (float*)d_out;

    ushort_t* wsW = (ushort_t*)d_ws;                          // 512 KB
    float* wsc    = (float*)((char*)d_ws + WSW_BYTES);        // 512 B

    (void)hipFuncSetAttribute((const void*)conv_main_kernel,
                              hipFuncAttributeMaxDynamicSharedMemorySize, SMEM_BYTES);

    prep_w_kernel<<<64, 256, 0, stream>>>(w, wsW);
    prep_const_kernel<<<1, 128, 0, stream>>>(bias, wsc);

    dim3 grid(5, 9, 32);   // q-tiles, p-tiles, n
    conv_main_kernel<<<grid, 256, SMEM_BYTES, stream>>>(x, bias, wsW, wsc, out);

    fill_kernel<<<65536, 256, 0, stream>>>(wsc, out);
}